// Round 5
// baseline (570.704 us; speedup 1.0000x reference)
//
#include <hip/hip_runtime.h>

typedef __attribute__((ext_vector_type(4))) short short4v;
typedef __attribute__((ext_vector_type(8))) short short8;
typedef __attribute__((ext_vector_type(4))) float floatx4;

#define NB 16384
#define TT 24
#define HH 128
#define LDA 40    // As row stride (u16); 80 B, 16B-aligned rows
#define LDH 136   // h row stride (u16); 272 B, 16B-aligned rows
#define ASZ (64 * LDA)
#define HSZ (64 * LDH)

__device__ __forceinline__ float bf2f(unsigned short u) {
    union { unsigned int i; float f; } v; v.i = ((unsigned int)u) << 16; return v.f;
}
__device__ __forceinline__ unsigned short f2bf(float f) {
    union { float f; unsigned int i; } v; v.f = f;
    unsigned int x = v.i;
    return (unsigned short)((x + 0x7fffu + ((x >> 16) & 1u)) >> 16);
}
__device__ __forceinline__ float fsig(float x) {
    return __fdividef(1.f, 1.f + __expf(-x));
}
__device__ __forceinline__ float ftanh(float x) {
    x = fminf(15.f, fmaxf(-15.f, x));
    float e = __expf(2.f * x);
    return __fdividef(e - 1.f, e + 1.f);
}
__device__ __forceinline__ short4v pk4(floatx4 a) {
    short4v r;
    r[0] = (short)f2bf(a[0]); r[1] = (short)f2bf(a[1]);
    r[2] = (short)f2bf(a[2]); r[3] = (short)f2bf(a[3]);
    return r;
}
// swizzled h-LDS address (u16 units): 16B chunk index XOR'd with row bit3.
// Makes the column-wise scalar h-writes bank-conflict-free while keeping
// 16B-aligned ds_read_b128 on the A-fragment side (<=2-way, free).
__device__ __forceinline__ int haddr(int row, int k) {
    int chunk = (k >> 3) ^ ((row & 8) >> 2);
    return row * LDH + (chunk << 3) + (k & 7);
}

// ---- k_prep: convert f32 weights to packed bf16 in ws (1.18 MB).
// Wc  : 512 x 1056  (rows 0..383 = W_ih[:, :1056]; 384..511 = W_dh)
// Whh : 384 x 128 ; Wms : 4 x 128 (mu0, mu1, std0, std1)
__global__ void k_prep(const float* __restrict__ W_ih, const float* __restrict__ W_dh,
                       const float* __restrict__ W_hh, const float* __restrict__ W_mu,
                       const float* __restrict__ W_std, unsigned short* __restrict__ Wc,
                       unsigned short* __restrict__ Whh, unsigned short* __restrict__ Wms) {
    int blk = blockIdx.x;
    if (blk < 512) {
        const float* src = (blk < 384) ? (W_ih + (size_t)blk * 1060)
                                       : (W_dh + (size_t)(blk - 384) * 1056);
        unsigned short* dst = Wc + (size_t)blk * 1056;
        for (int k = threadIdx.x; k < 1056; k += 256) dst[k] = f2bf(src[k]);
    } else if (blk < 896) {
        int r = blk - 512;
        if (threadIdx.x < 128) Whh[r * 128 + threadIdx.x] = f2bf(W_hh[r * 128 + threadIdx.x]);
    } else {
        for (int i = threadIdx.x; i < 512; i += 256) {
            int r = i >> 7, k = i & 127;
            Wms[i] = f2bf(r < 2 ? W_mu[r * 128 + k] : W_std[(r - 2) * 128 + k]);
        }
    }
}

// ---- fused decoder: 256 blocks x 512 threads; block owns 64 batch rows.
__global__ __launch_bounds__(512, 2) void k_fused(
    const float* __restrict__ last, const float* __restrict__ enc,
    const float* __restrict__ zin, const float* __restrict__ sg,
    const float* __restrict__ fut, const float* __restrict__ b_dh,
    const float* __restrict__ W_vel, const float* __restrict__ b_vel,
    const float* __restrict__ W_ih, const float* __restrict__ b_ih,
    const float* __restrict__ b_hh, const float* __restrict__ b_mu,
    const float* __restrict__ b_std, const unsigned short* __restrict__ Wc,
    const unsigned short* __restrict__ Whh, const unsigned short* __restrict__ Wms,
    float* __restrict__ out) {
    __shared__ unsigned short As[2 * ASZ];
    __shared__ unsigned short h2[2 * HSZ];
    __shared__ float a_lds[2][64][2];
    __shared__ float rel_lds[64][2];

    const int tid = threadIdx.x;
    const int w = tid >> 6, lane = tid & 63;
    const int col = lane & 15, q = lane >> 4;
    const int b0 = blockIdx.x * 64;
    const int jc = w * 16 + col;

    // a0 = last_obs @ W_vel.T + b_vel ; rel = (sg - last[:, :2]) / 4.8
    if (tid < 128) {
        int row = tid >> 1, c = tid & 1;
        int b = b0 + row;
        float s = b_vel[c];
#pragma unroll
        for (int s2 = 0; s2 < 6; s2++) s += last[b * 6 + s2] * W_vel[c * 6 + s2];
        a_lds[0][row][c] = s;
        rel_lds[row][c] = (sg[b * 2 + c] - last[b * 6 + c]) * (1.f / 4.8f);
    }

    // ---------------- phase 1: K=1056 GEMM into registers ----------------
    floatx4 acc2[4][4];  // [mt][gg]: gg 0..2 gates, gg=3 -> h0
#pragma unroll
    for (int i = 0; i < 4; i++)
#pragma unroll
        for (int j = 0; j < 4; j++) acc2[i][j] = (floatx4){0.f, 0.f, 0.f, 0.f};

    const int arow = tid >> 3, koff = (tid & 7) * 4;

    // preload ki=0 A tile -> buf 0
    {
        floatx4 a0 = *(const floatx4*)(enc + (size_t)(b0 + arow) * 1024 + koff);
        *(short4v*)(As + arow * LDA + koff) = pk4(a0);
    }
    __syncthreads();

    for (int ki = 0; ki < 33; ki++) {
        const int cur = ki & 1, nxt = cur ^ 1;
        floatx4 an;
        if (ki < 32) {
            an = (ki + 1 < 32)
                ? *(const floatx4*)(enc + (size_t)(b0 + arow) * 1024 + (ki + 1) * 32 + koff)
                : *(const floatx4*)(zin + (size_t)(b0 + arow) * 32 + koff);
        }
        short8 bb[4];
#pragma unroll
        for (int gg = 0; gg < 4; gg++)
            bb[gg] = *(const short8*)(Wc + (size_t)(gg * 128 + jc) * 1056 + ki * 32 + q * 8);
        short8 af[4];
#pragma unroll
        for (int mt = 0; mt < 4; mt++)
            af[mt] = *(const short8*)(As + cur * ASZ + (mt * 16 + col) * LDA + q * 8);
#pragma unroll
        for (int gg = 0; gg < 4; gg++)
#pragma unroll
            for (int mt = 0; mt < 4; mt++)
                acc2[mt][gg] = __builtin_amdgcn_mfma_f32_16x16x32_bf16(
                    af[mt], bb[gg], acc2[mt][gg], 0, 0, 0);
        if (ki < 32) *(short4v*)(As + nxt * ASZ + arow * LDA + koff) = pk4(an);
        __syncthreads();
    }

    // phase-1 epilogue -> greg / hprev registers, h0 -> h2 buf0 (bf16, swizzled)
    float bihg[3], wr0g[3], wr1g[3], wa0[3], wa1[3], bhh_n;
#pragma unroll
    for (int g = 0; g < 3; g++) {
        const size_t rb = (size_t)(g * HH + jc) * 1060;
        bihg[g] = b_ih[g * HH + jc] + ((g < 2) ? b_hh[g * HH + jc] : 0.f);
        wa0[g] = W_ih[rb + 1056];
        wa1[g] = W_ih[rb + 1057];
        wr0g[g] = W_ih[rb + 1058];
        wr1g[g] = W_ih[rb + 1059];
    }
    bhh_n = b_hh[2 * HH + jc];

    float greg[4][3][4];
    float hprev[4][4];
    const float bdh = b_dh[jc];
#pragma unroll
    for (int mt = 0; mt < 4; mt++) {
#pragma unroll
        for (int r = 0; r < 4; r++) {
            int blr = mt * 16 + q * 4 + r;
            float r0 = rel_lds[blr][0], r1 = rel_lds[blr][1];
#pragma unroll
            for (int g = 0; g < 3; g++)
                greg[mt][g][r] = acc2[mt][g][r] + bihg[g] + r0 * wr0g[g] + r1 * wr1g[g];
            float h0v = acc2[mt][3][r] + bdh;
            hprev[mt][r] = h0v;
            h2[haddr(blr, jc)] = f2bf(h0v);
        }
    }

    // resident W_hh fragments
    short8 bfr[3][4];
#pragma unroll
    for (int g = 0; g < 3; g++)
#pragma unroll
        for (int kt = 0; kt < 4; kt++)
            bfr[g][kt] = *(const short8*)(Whh + (size_t)(g * HH + jc) * HH + kt * 32 + q * 8);

    // mu/std fragments + bias (waves 0,1 only; lanes col<4 carry real rows)
    short8 msf[4];
    float msbias = 0.f;
    if (w < 2) {
#pragma unroll
        for (int kt = 0; kt < 4; kt++)
            msf[kt] = (col < 4) ? *(const short8*)(Wms + col * 128 + kt * 32 + q * 8)
                                : (short8){0, 0, 0, 0, 0, 0, 0, 0};
        if (col < 4) msbias = (col >= 2) ? b_std[col & 1] : b_mu[col & 1];
    }

    __syncthreads();  // h0 visible

    // ---------------- phase 2: 24-step recurrence, 1 barrier/step ----------------
    for (int t = 0; t < TT; t++) {
        const unsigned short* hc = h2 + (t & 1) * HSZ;
        unsigned short* hn = h2 + ((t + 1) & 1) * HSZ;

        floatx4 acc[4][3];
        floatx4 accms[2];
#pragma unroll
        for (int mt = 0; mt < 4; mt++)
#pragma unroll
            for (int g = 0; g < 3; g++) acc[mt][g] = (floatx4){0.f, 0.f, 0.f, 0.f};
        accms[0] = (floatx4){0.f, 0.f, 0.f, 0.f};
        accms[1] = (floatx4){0.f, 0.f, 0.f, 0.f};

#pragma unroll
        for (int kt = 0; kt < 4; kt++) {
            short8 af2[4];
#pragma unroll
            for (int mt = 0; mt < 4; mt++)
                af2[mt] = *(const short8*)(hc + haddr(mt * 16 + col, kt * 32 + q * 8));
#pragma unroll
            for (int mt = 0; mt < 4; mt++)
#pragma unroll
                for (int g = 0; g < 3; g++)
                    acc[mt][g] = __builtin_amdgcn_mfma_f32_16x16x32_bf16(
                        af2[mt], bfr[g][kt], acc[mt][g], 0, 0, 0);
            if (w < 2 && t > 0) {
#pragma unroll
                for (int mtl = 0; mtl < 2; mtl++)
                    accms[mtl] = __builtin_amdgcn_mfma_f32_16x16x32_bf16(
                        af2[w * 2 + mtl], msf[kt], accms[mtl], 0, 0, 0);
            }
        }

        // mu/std for h_t (t>=1) -> out row t-1
        if (w < 2 && t > 0 && col < 4) {
            int kind = col >> 1, c = col & 1;
#pragma unroll
            for (int mtl = 0; mtl < 2; mtl++)
#pragma unroll
                for (int r = 0; r < 4; r++) {
                    float val = accms[mtl][r] + msbias;
                    if (kind) val = __expf(0.5f * val);
                    int b = b0 + (w * 2 + mtl) * 16 + q * 4 + r;
                    out[(size_t)kind * (TT * NB * 2) + (size_t)(t - 1) * NB * 2 + b * 2 + c] = val;
                }
        }

        // gates
#pragma unroll
        for (int mt = 0; mt < 4; mt++) {
#pragma unroll
            for (int r = 0; r < 4; r++) {
                int blr = mt * 16 + q * 4 + r;
                float a0v = a_lds[t & 1][blr][0], a1v = a_lds[t & 1][blr][1];
                float gir = greg[mt][0][r] + a0v * wa0[0] + a1v * wa1[0] + acc[mt][0][r];
                float giz = greg[mt][1][r] + a0v * wa0[1] + a1v * wa1[1] + acc[mt][1][r];
                float gin = greg[mt][2][r] + a0v * wa0[2] + a1v * wa1[2];
                float ghn = acc[mt][2][r] + bhh_n;
                float rg = fsig(gir);
                float zg = fsig(giz);
                float ng = ftanh(gin + rg * ghn);
                hprev[mt][r] = (1.f - zg) * ng + zg * hprev[mt][r];
            }
        }

        // write h_{t+1} into the other buffer (no WAR hazard), stage next a
#pragma unroll
        for (int mt = 0; mt < 4; mt++)
#pragma unroll
            for (int r = 0; r < 4; r++)
                hn[haddr(mt * 16 + q * 4 + r, jc)] = f2bf(hprev[mt][r]);
        if (tid < 128) {
            int row = tid >> 1, c = tid & 1;
            a_lds[(t + 1) & 1][row][c] = fut[((size_t)t * NB + b0 + row) * 6 + 2 + c];
        }

        __syncthreads();
    }

    // final mu/std pass for h_TT -> out row TT-1  (h_TT lives in buf TT&1 = 0)
    if (w < 2) {
        const unsigned short* hc = h2 + (TT & 1) * HSZ;
        floatx4 accms[2];
        accms[0] = (floatx4){0.f, 0.f, 0.f, 0.f};
        accms[1] = (floatx4){0.f, 0.f, 0.f, 0.f};
#pragma unroll
        for (int kt = 0; kt < 4; kt++) {
#pragma unroll
            for (int mtl = 0; mtl < 2; mtl++) {
                short8 af2 = *(const short8*)(hc + haddr((w * 2 + mtl) * 16 + col, kt * 32 + q * 8));
                accms[mtl] = __builtin_amdgcn_mfma_f32_16x16x32_bf16(
                    af2, msf[kt], accms[mtl], 0, 0, 0);
            }
        }
        if (col < 4) {
            int kind = col >> 1, c = col & 1;
#pragma unroll
            for (int mtl = 0; mtl < 2; mtl++)
#pragma unroll
                for (int r = 0; r < 4; r++) {
                    float val = accms[mtl][r] + msbias;
                    if (kind) val = __expf(0.5f * val);
                    int b = b0 + (w * 2 + mtl) * 16 + q * 4 + r;
                    out[(size_t)kind * (TT * NB * 2) + (size_t)(TT - 1) * NB * 2 + b * 2 + c] = val;
                }
        }
    }
}

extern "C" void kernel_launch(void* const* d_in, const int* in_sizes, int n_in,
                              void* d_out, int out_size, void* d_ws, size_t ws_size,
                              hipStream_t stream) {
    (void)in_sizes; (void)n_in; (void)out_size; (void)ws_size;
    const float* last  = (const float*)d_in[0];
    const float* enc   = (const float*)d_in[1];
    const float* zin   = (const float*)d_in[2];
    const float* sg    = (const float*)d_in[3];
    const float* fut   = (const float*)d_in[4];
    const float* W_dh  = (const float*)d_in[5];
    const float* b_dh  = (const float*)d_in[6];
    const float* W_vel = (const float*)d_in[7];
    const float* b_vel = (const float*)d_in[8];
    const float* W_ih  = (const float*)d_in[9];
    const float* b_ih  = (const float*)d_in[10];
    const float* W_hh  = (const float*)d_in[11];
    const float* b_hh  = (const float*)d_in[12];
    const float* W_mu  = (const float*)d_in[13];
    const float* b_mu  = (const float*)d_in[14];
    const float* W_std = (const float*)d_in[15];
    const float* b_std = (const float*)d_in[16];
    float* out = (float*)d_out;

    char* ws = (char*)d_ws;
    unsigned short* Wc  = (unsigned short*)ws;              // 512*1056*2 = 1,081,344 B
    unsigned short* Whh = (unsigned short*)(ws + 1081344);  // 384*128*2  =    98,304 B
    unsigned short* Wms = (unsigned short*)(ws + 1179648);  // 4*128*2    =     1,024 B

    k_prep<<<897, 256, 0, stream>>>(W_ih, W_dh, W_hh, W_mu, W_std, Wc, Whh, Wms);
    k_fused<<<256, 512, 0, stream>>>(last, enc, zin, sg, fut, b_dh, W_vel, b_vel,
                                     W_ih, b_ih, b_hh, b_mu, b_std, Wc, Whh, Wms, out);
}